// Round 3
// baseline (685.109 us; speedup 1.0000x reference)
//
#include <hip/hip_runtime.h>
#include <hip/hip_bf16.h>

#define BB 2
#define SS 2048
#define HH 1024
#define EE 8
#define KK 2
#define CAP 1536
#define NTOK (BB * SS)        // 4096
#define NASSIGN (NTOK * KK)   // 8192

// ---------------- workspace layout (float indices) ----------------
#define WS_PSUM   0            // 8
#define WS_AVG    8            // 2048  (fallback path full sums; unused in mfma path)
#define WS_HC     2056         // 2048  (raw pre-bias pre-relu, atomic target)
#define WS_ADJ    4104         // 16
#define WS_P1     4120         // 4096
#define WS_P2     8216         // 4096
#define WS_IDX    12312        // 4096 ints
#define WS_LOGITS 16408        // 32768: fallback logits OR avg partials (16*2*1024)
#define WS_ZERO_FLOATS 4112    // psum+avg+hc+adj head (zeroed by prep blk0 / memset)
#define WS_ZERO_BYTES 16448
#define WS_BF16_BYTE 196704    // bf16 planes start here (16B aligned)
// planes: Xh/Xm/Xl 3*8388608 B + Wh/Wm/Wl 3*2097152 B = 31457280 B
#define WS_H_BYTE (WS_BF16_BYTE + 31457280)   // mfma logits (131072 B) + posTab + pTab
#define WS_NEED (WS_H_BYTE + 16777216ull)

using short8 = __attribute__((ext_vector_type(8))) short;
using u16x8  = __attribute__((ext_vector_type(8))) unsigned short;
using f32x4  = __attribute__((ext_vector_type(4))) float;

// ---- bf16 split helpers (manual RNE) ----
__device__ __forceinline__ unsigned short f2bf(float f) {
  unsigned u = __float_as_uint(f);
  unsigned r = (u + 0x7fffu + ((u >> 16) & 1u)) >> 16;
  return (unsigned short)r;
}
__device__ __forceinline__ float bf2f(unsigned short h) {
  return __uint_as_float((unsigned)h << 16);
}
__device__ __forceinline__ void split3(float x, unsigned short& h,
                                       unsigned short& m, unsigned short& l) {
  h = f2bf(x);
  float r = x - bf2f(h);
  m = f2bf(r);
  l = f2bf(r - bf2f(m));
}

// async global->LDS, 16B per lane; lptr is wave-uniform base, HW adds lane*16
__device__ __forceinline__ void gload_lds16(const void* g, void* l) {
  __builtin_amdgcn_global_load_lds(
      (const __attribute__((address_space(1))) void*)g,
      (__attribute__((address_space(3))) void*)l, 16, 0, 0);
}

// ---------------- D1: consolidated prep dispatch ----------------
// blocks [0,4096): split X -> bf16 planes (blk0 zeros ws scalar head,
//                  blks 1..32 zero the 32768-float logits buffer)
// blocks [4096,4352): split+transpose w1 -> bf16 planes
// blocks [4352,4480): avg partial sums (no atomics, no zero-init needed)
#define PREPX_BLKS 4096
#define PREPW_BLKS 256
#define AVG_BLKS   128
__global__ __launch_bounds__(256) void k_prep(
    const float* __restrict__ x, const float* __restrict__ w1,
    unsigned short* __restrict__ Xh, unsigned short* __restrict__ Xm,
    unsigned short* __restrict__ Xl,
    unsigned short* __restrict__ Wh, unsigned short* __restrict__ Wm,
    unsigned short* __restrict__ Wl,
    float* __restrict__ wshead, float* __restrict__ avg_part,
    float* __restrict__ lgz) {
  __shared__ unsigned short Th[64 * 65], Tm[64 * 65], Tl[64 * 65];
  int tid = threadIdx.x;
  int bid = blockIdx.x;
  if (bid < PREPX_BLKS) {
    if (bid == 0)
      for (int j = tid; j < WS_ZERO_FLOATS; j += 256) wshead[j] = 0.f;
    if (bid >= 1 && bid <= 32) {
      const float4 z = {0.f, 0.f, 0.f, 0.f};
      ((float4*)lgz)[(bid - 1) * 256 + tid] = z;   // zero 4096x8 logits
    }
    int i = (bid * 256 + tid) * 4;
    float4 v = *(const float4*)&x[i];
    unsigned short h[4], m[4], l[4];
    split3(v.x, h[0], m[0], l[0]);
    split3(v.y, h[1], m[1], l[1]);
    split3(v.z, h[2], m[2], l[2]);
    split3(v.w, h[3], m[3], l[3]);
    *(ushort4*)&Xh[i] = make_ushort4(h[0], h[1], h[2], h[3]);
    *(ushort4*)&Xm[i] = make_ushort4(m[0], m[1], m[2], m[3]);
    *(ushort4*)&Xl[i] = make_ushort4(l[0], l[1], l[2], l[3]);
  } else if (bid < PREPX_BLKS + PREPW_BLKS) {
    int pid = bid - PREPX_BLKS;
    int k0 = (pid & 15) * 64, n0 = (pid >> 4) * 64;
    for (int i = 0; i < 16; ++i) {
      int e = i * 256 + tid;
      int k = e >> 6, n = e & 63;
      float v = w1[(size_t)(k0 + k) * HH + n0 + n];
      unsigned short h, m, l;
      split3(v, h, m, l);
      Th[n * 65 + k] = h; Tm[n * 65 + k] = m; Tl[n * 65 + k] = l;
    }
    __syncthreads();
    for (int i = 0; i < 16; ++i) {
      int e = i * 256 + tid;
      int n = e >> 6, k = e & 63;
      size_t o = (size_t)(n0 + n) * HH + k0 + k;
      Wh[o] = Th[n * 65 + k]; Wm[o] = Tm[n * 65 + k]; Wl[o] = Tl[n * 65 + k];
    }
  } else {
    int pid = bid - PREPX_BLKS - PREPW_BLKS;  // 0..127
    int h = (pid & 3) * 256 + tid;
    int c = (pid >> 2) & 15;
    int b = pid >> 6;
    const float* p = x + (size_t)b * SS * HH + (size_t)(c * 128) * HH + h;
    float s = 0.f;
    for (int i = 0; i < 128; ++i) s += p[(size_t)i * HH];
    avg_part[(c * BB + b) * HH + h] = s;   // raw partial sum
  }
}

// standalone avg-partials kernel (fallback path only)
__global__ void k_avgp(const float* __restrict__ x, float* __restrict__ avg_part) {
  int h = blockIdx.x * 256 + threadIdx.x;
  int c = blockIdx.y;
  int b = blockIdx.z;
  const float* p = x + (size_t)b * SS * HH + (size_t)(c * 128) * HH + h;
  float s = 0.f;
  for (int i = 0; i < 128; ++i) s += p[(size_t)i * HH];
  avg_part[(c * BB + b) * HH + h] = s;
}

// hc_raw += partial dot over i-chunk; reduces the 16 avg partials through LDS
__global__ void k_hc(const float* __restrict__ avg_part, const float* __restrict__ chr,
                     const float* __restrict__ wc1, float* __restrict__ hc_raw) {
  __shared__ float avg_s[128];
  int tid = threadIdx.x;
  int j = blockIdx.x * 256 + tid;
  int c = blockIdx.y;
  int b = blockIdx.z;
  if (tid < 128) {
    float s = 0.f;
    for (int cc = 0; cc < 16; ++cc)
      s += avg_part[(cc * BB + b) * HH + c * 128 + tid];
    avg_s[tid] = s * (1.0f / SS);
  }
  __syncthreads();
  float acc = 0.f;
  for (int il = 0; il < 128; ++il)
    acc += avg_s[il] * wc1[(size_t)(c * 128 + il) * HH + j];
  if (c == 7)
    for (int i = 0; i < EE; ++i)
      acc += chr[i] * wc1[(size_t)(HH + i) * HH + j];
  atomicAdd(&hc_raw[b * HH + j], acc);
}

// standalone adj kernel (fallback path only; mfma path runs adj inside D3)
__global__ void k_adj(const float* __restrict__ hc_raw, const float* __restrict__ bc1,
                      const float* __restrict__ wc2, const float* __restrict__ bc2,
                      float* __restrict__ adj) {
  int b = blockIdx.x;
  int tid = threadIdx.x;
  float part[EE] = {};
  for (int j = tid; j < HH; j += 256) {
    float v = fmaxf(hc_raw[b * HH + j] + bc1[j], 0.f);
    for (int e = 0; e < EE; ++e) part[e] += v * wc2[j * EE + e];
  }
  for (int m = 1; m < 64; m <<= 1)
    for (int e = 0; e < EE; ++e) part[e] += __shfl_xor(part[e], m);
  __shared__ float red[4][EE];
  int wave = tid >> 6, lane = tid & 63;
  if (lane == 0)
    for (int e = 0; e < EE; ++e) red[wave][e] = part[e];
  __syncthreads();
  if (tid < EE) {
    float s = bc2[tid];
    for (int w = 0; w < 4; ++w) s += red[w][tid];
    adj[b * EE + tid] = tanhf(s);
  }
}

// ---------------- D3: clean MFMA GEMM dispatch -------------------
// Grid = BB adj blocks + 512 GEMM blocks.
//  - GEMM: double-buffered prefetch K-loop, one barrier per K-step; the
//    vmcnt(0) at the barrier now drains ONLY the 9 prefetch loads issued a
//    full compute phase earlier (no NT stores in the loop anymore).
//  - LDS XOR swizzle (both-sides, rule #21): global-source k-quarter permuted
//    per lane, same involution on ds_read -> 2-way (free) instead of 8-way.
//  - Epilogue: relu(+b1), then per-64col partial logits via w2 tile,
//    atomicAdd into the logits buffer (no hbuf round trip).
#define BM 128
#define BN 64
#define BK 32
#define NGEMM 512
__global__ __launch_bounds__(256) void k_fused(
    const unsigned short* __restrict__ Xh, const unsigned short* __restrict__ Xm,
    const unsigned short* __restrict__ Xl,
    const unsigned short* __restrict__ Wh, const unsigned short* __restrict__ Wm,
    const unsigned short* __restrict__ Wl,
    const float* __restrict__ b1, const float* __restrict__ w2,
    const float* __restrict__ hc_raw, const float* __restrict__ bc1,
    const float* __restrict__ wc2, const float* __restrict__ bc2,
    float* __restrict__ adj, float* __restrict__ logits) {
  __shared__ unsigned short As[2][3][BM * BK];   // 2 x 24KB
  __shared__ unsigned short Bs[2][3][BN * BK];   // 2 x 12KB
  __shared__ float b1s[BN];
  __shared__ float w2s[BN * 9];                  // padded stride 9
  __shared__ float red[4][EE];
  int tid = threadIdx.x;
  int bid = blockIdx.x;

  if (bid < BB) {  // ---- adj blocks ----
    int b = bid;
    float part[EE] = {};
    for (int j = tid; j < HH; j += 256) {
      float v = fmaxf(hc_raw[b * HH + j] + bc1[j], 0.f);
      for (int e = 0; e < EE; ++e) part[e] += v * wc2[j * EE + e];
    }
    for (int m = 1; m < 64; m <<= 1)
      for (int e = 0; e < EE; ++e) part[e] += __shfl_xor(part[e], m);
    int wave = tid >> 6, lane = tid & 63;
    if (lane == 0)
      for (int e = 0; e < EE; ++e) red[wave][e] = part[e];
    __syncthreads();
    if (tid < EE) {
      float s = bc2[tid];
      for (int w = 0; w < 4; ++w) s += red[w][tid];
      adj[b * EE + tid] = tanhf(s);
    }
    return;
  }

  // ---- GEMM blocks ----
  int g = bid - BB;                    // 0..511
  int gs = (g & 7) * 64 + (g >> 3);    // XCD-chunked swizzle (512 = 8*64)
  int m0 = (gs >> 4) * BM, n0 = (gs & 15) * BN;

  if (tid < BN) b1s[tid] = b1[n0 + tid];
#pragma unroll
  for (int rdx = 0; rdx < 2; ++rdx) {  // stage w2 tile: 64x8
    int i = tid + rdx * 256;
    int c = i >> 3, e = i & 7;
    w2s[c * 9 + e] = w2[(size_t)(n0 + c) * EE + e];
  }

  int lane = tid & 63, wave = tid >> 6;
  int wm = wave & 1, wn = wave >> 1;   // wave tile: 64 rows x 32 cols
  int q = lane >> 4, mr = lane & 15;
  // staging: row-within-group; k-quarter pre-swizzled at the GLOBAL source
  // (LDS dest stays linear for global_load_lds). Involution: q' = q ^ ((r>>1)&3).
  int lr = lane >> 2;
  int lqs = (lane & 3) ^ ((lane >> 3) & 3);

  f32x4 acc[4][2] = {};
  const unsigned short* Ag[3] = {Xh, Xm, Xl};
  const unsigned short* Bg[3] = {Wh, Wm, Wl};

  auto STAGE = [&](int t, int bf) {
    int k0 = t * BK;
    // A: 24 wave-instrs (3 planes x 8 groups of 16 rows); this wave does 6
#pragma unroll
    for (int j = 0; j < 6; ++j) {
      int i = wave + 4 * j;
      int s = i >> 3, gg = i & 7;
      gload_lds16(Ag[s] + (size_t)(m0 + gg * 16 + lr) * HH + k0 + lqs * 8,
                  &As[bf][s][gg * 512]);
    }
    // B: 12 wave-instrs (3 planes x 4 groups of 16 rows); this wave does 3
#pragma unroll
    for (int j = 0; j < 3; ++j) {
      int i = wave + 4 * j;
      int s = i >> 2, gg = i & 3;
      gload_lds16(Bg[s] + (size_t)(n0 + gg * 16 + lr) * HH + k0 + lqs * 8,
                  &Bs[bf][s][gg * 512]);
    }
  };

  // swizzled read quarter for this lane's fragment rows (row = mr)
  int qsw = (q ^ ((mr >> 1) & 3)) * 8;

  STAGE(0, 0);
  __syncthreads();   // vmcnt(0): tile 0 staged (also publishes b1s/w2s)
  int cur = 0;
  for (int t = 0; t < HH / BK; ++t) {
    if (t + 1 < HH / BK) STAGE(t + 1, cur ^ 1);  // prefetch next tile

    short8 af[3][4], bv[3][2];
#pragma unroll
    for (int s = 0; s < 3; ++s) {
#pragma unroll
      for (int mi = 0; mi < 4; ++mi)
        af[s][mi] = *(const short8*)&As[cur][s][(wm * 4 + mi) * 512 + mr * 32 + qsw];
#pragma unroll
      for (int ni = 0; ni < 2; ++ni)
        bv[s][ni] = *(const short8*)&Bs[cur][s][(wn * 2 + ni) * 512 + mr * 32 + qsw];
    }
#pragma unroll
    for (int mi = 0; mi < 4; ++mi)
#pragma unroll
      for (int ni = 0; ni < 2; ++ni) {
        f32x4 c = acc[mi][ni];
        c = __builtin_amdgcn_mfma_f32_16x16x32_bf16(af[0][mi], bv[0][ni], c, 0, 0, 0); // h.h
        c = __builtin_amdgcn_mfma_f32_16x16x32_bf16(af[0][mi], bv[1][ni], c, 0, 0, 0); // h.m
        c = __builtin_amdgcn_mfma_f32_16x16x32_bf16(af[1][mi], bv[0][ni], c, 0, 0, 0); // m.h
        c = __builtin_amdgcn_mfma_f32_16x16x32_bf16(af[0][mi], bv[2][ni], c, 0, 0, 0); // h.l
        c = __builtin_amdgcn_mfma_f32_16x16x32_bf16(af[2][mi], bv[0][ni], c, 0, 0, 0); // l.h
        c = __builtin_amdgcn_mfma_f32_16x16x32_bf16(af[1][mi], bv[1][ni], c, 0, 0, 0); // m.m
        acc[mi][ni] = c;
      }
    __syncthreads();   // drains vmcnt(0): tile t+1 staged; buf[cur] free to reuse
    cur ^= 1;
  }

  // epilogue: relu(+b1) then partial logits over this block's 64 cols.
  // lane holds rows (wm*64+mi*16+q*4+r), cols c0=wn*32+mr, c1=c0+16.
#pragma unroll
  for (int mi = 0; mi < 4; ++mi)
#pragma unroll
    for (int r = 0; r < 4; ++r) {
      int rowl = wm * 64 + mi * 16 + q * 4 + r;
      int c0 = wn * 32 + mr, c1 = c0 + 16;
      float v0 = fmaxf(acc[mi][0][r] + b1s[c0], 0.f);
      float v1 = fmaxf(acc[mi][1][r] + b1s[c1], 0.f);
      float pe[EE];
#pragma unroll
      for (int e = 0; e < EE; ++e)
        pe[e] = v0 * w2s[c0 * 9 + e] + v1 * w2s[c1 * 9 + e];
#pragma unroll
      for (int m = 1; m < 16; m <<= 1)
#pragma unroll
        for (int e = 0; e < EE; ++e) pe[e] += __shfl_xor(pe[e], m);
      if (mr == 0) {
        float* lp = &logits[(size_t)(m0 + rowl) * EE];
#pragma unroll
        for (int e = 0; e < EE; ++e) atomicAdd(&lp[e], pe[e]);
      }
    }
}

// ---------------- D4: fused softmax + top2 + serial capacity ------------
// One block, 256 threads; thread tid owns tokens [tid*16, tid*16+16) =
// assignments [tid*32, +32) -- matches the reference's serial (b,s,k) order.
// Phase 0: softmax+top2 per token (registers, fully unrolled), probs out.
// Phase 1: per-expert counts -> LDS exclusive scan over threads.
// Phase 2: per-assignment serial slot -> posTab/pTab (consumed by k_write).
// Also computes psum (wave reduce) and aux.
__global__ __launch_bounds__(256) void k_route2(
    const float* __restrict__ logits, const float* __restrict__ b2,
    const float* __restrict__ adj, float* __restrict__ probs_out,
    int* __restrict__ posTab, float* __restrict__ pTab,
    float* __restrict__ aux_out) {
  __shared__ int cnt[256][EE];   // 8KB
  __shared__ int tot[EE];
  __shared__ float psums[4][EE];
  int tid = threadIdx.x;
  int lane = tid & 63, wave = tid >> 6;

  float a0[EE], a1[EE], b2r[EE];
#pragma unroll
  for (int e = 0; e < EE; ++e) {
    b2r[e] = b2[e]; a0[e] = adj[e]; a1[e] = adj[EE + e];
  }

  int   myi[16];
  float myp1[16], myp2[16];
  int local[EE] = {};
  float psum_l[EE] = {};

#pragma unroll
  for (int i = 0; i < 16; ++i) {
    int t = tid * 16 + i;
    int hi = t >> 11;   // batch index
    float4 la = *(const float4*)&logits[(size_t)t * EE];
    float4 lb = *(const float4*)&logits[(size_t)t * EE + 4];
    float l[EE] = {la.x, la.y, la.z, la.w, lb.x, lb.y, lb.z, lb.w};
    float mx = -1e30f;
#pragma unroll
    for (int e = 0; e < EE; ++e) {
      float av = hi ? a1[e] : a0[e];
      l[e] += b2r[e] + av;          // same add order as before (bit-exact)
      mx = fmaxf(mx, l[e]);
    }
    float s = 0.f;
#pragma unroll
    for (int e = 0; e < EE; ++e) { l[e] = expf(l[e] - mx); s += l[e]; }
    float inv = 1.f / s;
#pragma unroll
    for (int e = 0; e < EE; ++e) { l[e] *= inv; psum_l[e] += l[e]; }
    float4 pa = {l[0], l[1], l[2], l[3]}, pb = {l[4], l[5], l[6], l[7]};
    *(float4*)&probs_out[(size_t)t * EE] = pa;
    *(float4*)&probs_out[(size_t)t * EE + 4] = pb;
    int e1 = 0; float p1 = l[0];
#pragma unroll
    for (int e = 1; e < EE; ++e) if (l[e] > p1) { p1 = l[e]; e1 = e; }
    int e2 = -1; float p2 = -1.f;
#pragma unroll
    for (int e = 0; e < EE; ++e) if (e != e1 && l[e] > p2) { p2 = l[e]; e2 = e; }
    float norm = 1.f / (p1 + p2 + 1e-8f);
    myi[i] = e1 | (e2 << 8);
    myp1[i] = p1 * norm;
    myp2[i] = p2 * norm;
    local[e1]++; local[e2]++;
  }

#pragma unroll
  for (int e = 0; e < EE; ++e) cnt[tid][e] = local[e];
  // psum wave+block reduce (feeds aux only)
#pragma unroll
  for (int m = 1; m < 64; m <<= 1)
#pragma unroll
    for (int e = 0; e < EE; ++e) psum_l[e] += __shfl_xor(psum_l[e], m);
  if (lane == 0)
#pragma unroll
    for (int e = 0; e < EE; ++e) psums[wave][e] = psum_l[e];
  __syncthreads();
  if (tid < EE) {
    int run = 0;
    for (int t = 0; t < 256; ++t) { int v = cnt[t][tid]; cnt[t][tid] = run; run += v; }
    tot[tid] = run;
  }
  __syncthreads();
  int off[EE];
#pragma unroll
  for (int e = 0; e < EE; ++e) off[e] = cnt[tid][e];

#pragma unroll
  for (int i = 0; i < 16; ++i) {
    int t = tid * 16 + i;
    int pk = myi[i];
    int e1 = pk & 0xff, e2 = pk >> 8;
    int pos1 = off[e1]++;          // assignment n = 2t   (uses p1)
    int pos2 = off[e2]++;          // assignment n = 2t+1 (uses p2)
    int pv[EE];
    float pp[EE];
#pragma unroll
    for (int e = 0; e < EE; ++e) { pv[e] = -1; pp[e] = 0.f; }
    pv[e1] = (pos1 < CAP) ? pos1 : -1;
    pp[e1] = myp1[i];
    pv[e2] = (pos2 < CAP) ? pos2 : -1;
    pp[e2] = myp2[i];
    int4 pva = {pv[0], pv[1], pv[2], pv[3]}, pvb = {pv[4], pv[5], pv[6], pv[7]};
    float4 ppa = {pp[0], pp[1], pp[2], pp[3]}, ppb = {pp[4], pp[5], pp[6], pp[7]};
    *(int4*)&posTab[(size_t)t * EE] = pva;
    *(int4*)&posTab[(size_t)t * EE + 4] = pvb;
    *(float4*)&pTab[(size_t)t * EE] = ppa;
    *(float4*)&pTab[(size_t)t * EE + 4] = ppb;
  }

  if (tid == 0) {
    float aux = 0.f;
    for (int e = 0; e < EE; ++e) {
      float ps = psums[0][e] + psums[1][e] + psums[2][e] + psums[3][e];
      aux += (ps / (float)NTOK) * ((float)tot[e] / (float)NASSIGN);
    }
    aux_out[0] = aux * (float)EE;
  }
}

// ---------------- D5: dense streaming write of disp+comb ----------------
// Block t writes rows (t, e=0..7): 1536 floats each, zeros except the one
// routed slot. Single pass, coalesced 16B NT stores -> write-BW roofline.
__global__ __launch_bounds__(256) void k_write(
    const int* __restrict__ posTab, const float* __restrict__ pTab,
    float* __restrict__ disp, float* __restrict__ comb) {
  __shared__ int ps[EE];
  __shared__ float pv[EE];
  int t = blockIdx.x;
  int tid = threadIdx.x;
  if (tid < EE) {
    ps[tid] = posTab[(size_t)t * EE + tid];
    pv[tid] = pTab[(size_t)t * EE + tid];
  }
  __syncthreads();
  const int R4 = CAP / 4;            // 384 f4 per (t,e) row
  f32x4* dp = (f32x4*)disp + (size_t)t * EE * R4;
  f32x4* cp = (f32x4*)comb + (size_t)t * EE * R4;
#pragma unroll
  for (int j = 0; j < 12; ++j) {
    int i = j * 256 + tid;           // 0..3071
    int e = i / R4;
    int r4 = i - e * R4;
    int p = ps[e];
    f32x4 dv = {0.f, 0.f, 0.f, 0.f};
    f32x4 cv = {0.f, 0.f, 0.f, 0.f};
    if (p >= 0 && (p >> 2) == r4) {
      int pb = p & 3;
      float val = pv[e];
      dv[0] = (pb == 0) ? 1.f : 0.f; cv[0] = (pb == 0) ? val : 0.f;
      dv[1] = (pb == 1) ? 1.f : 0.f; cv[1] = (pb == 1) ? val : 0.f;
      dv[2] = (pb == 2) ? 1.f : 0.f; cv[2] = (pb == 2) ? val : 0.f;
      dv[3] = (pb == 3) ? 1.f : 0.f; cv[3] = (pb == 3) ? val : 0.f;
    }
    __builtin_nontemporal_store(dv, &dp[i]);
    __builtin_nontemporal_store(cv, &cp[i]);
  }
}

// ---------------- fp32 fallback GEMM (+ old softmax path) ----------------
__global__ __launch_bounds__(256) void k_gemm_f32(
    const float* __restrict__ X, const float* __restrict__ w1,
    const float* __restrict__ b1, const float* __restrict__ w2,
    float* __restrict__ logits) {
  __shared__ float Asf[16][65];
  __shared__ float Bsf[16][64];
  __shared__ float w2sf[64][EE];
  int tid = threadIdx.x;
  int m0 = blockIdx.x * 64, n0 = blockIdx.y * 64;
  for (int i = tid; i < 64 * EE; i += 256)
    w2sf[i / EE][i % EE] = w2[(size_t)(n0 + i / EE) * EE + (i % EE)];
  float acc[4][4] = {};
  int tx = tid & 15, ty = tid >> 4;
  for (int k0 = 0; k0 < HH; k0 += 16) {
    for (int idx = tid; idx < 64 * 16; idx += 256) {
      int m = idx >> 4, kk = idx & 15;
      Asf[kk][m] = X[(size_t)(m0 + m) * HH + k0 + kk];
    }
    for (int idx = tid; idx < 16 * 64; idx += 256) {
      int kk = idx >> 6, n = idx & 63;
      Bsf[kk][n] = w1[(size_t)(k0 + kk) * HH + n0 + n];
    }
    __syncthreads();
    for (int kk = 0; kk < 16; ++kk) {
      float a[4], bb[4];
      for (int i = 0; i < 4; ++i) a[i] = Asf[kk][ty * 4 + i];
      for (int j = 0; j < 4; ++j) bb[j] = Bsf[kk][tx * 4 + j];
      for (int i = 0; i < 4; ++i)
        for (int j = 0; j < 4; ++j) acc[i][j] += a[i] * bb[j];
    }
    __syncthreads();
  }
  float p[4][EE] = {};
  for (int i = 0; i < 4; ++i)
    for (int j = 0; j < 4; ++j) {
      int c = tx * 4 + j;
      float v = fmaxf(acc[i][j] + b1[n0 + c], 0.f);
      for (int e = 0; e < EE; ++e) p[i][e] += v * w2sf[c][e];
    }
  for (int m = 1; m < 16; m <<= 1)
    for (int i = 0; i < 4; ++i)
      for (int e = 0; e < EE; ++e) p[i][e] += __shfl_xor(p[i][e], m);
  if (tx == 0)
    for (int i = 0; i < 4; ++i)
      for (int e = 0; e < EE; ++e)
        atomicAdd(&logits[(size_t)(m0 + ty * 4 + i) * EE + e], p[i][e]);
}

__global__ void k_init_logits(const float* __restrict__ adj, const float* __restrict__ b2,
                              float* __restrict__ logits) {
  int i = blockIdx.x * 256 + threadIdx.x;
  int e = i & 7;
  int t = i >> 3;
  int b = t >> 11;
  logits[i] = b2[e] + adj[b * EE + e];
}

__global__ void k_softmax(const float* __restrict__ logits, float* __restrict__ probs_out,
                          int* __restrict__ idx_pack, float* __restrict__ p1o,
                          float* __restrict__ p2o, float* __restrict__ psum) {
  int t = blockIdx.x * 256 + threadIdx.x;
  float l[EE];
  float mx = -1e30f;
  for (int e = 0; e < EE; ++e) { l[e] = logits[t * EE + e]; mx = fmaxf(mx, l[e]); }
  float s = 0.f;
  for (int e = 0; e < EE; ++e) { l[e] = expf(l[e] - mx); s += l[e]; }
  float inv = 1.f / s;
  for (int e = 0; e < EE; ++e) { l[e] *= inv; probs_out[t * EE + e] = l[e]; }
  int e1 = 0; float p1 = l[0];
  for (int e = 1; e < EE; ++e) if (l[e] > p1) { p1 = l[e]; e1 = e; }
  int e2 = -1; float p2 = -1.f;
  for (int e = 0; e < EE; ++e) if (e != e1 && l[e] > p2) { p2 = l[e]; e2 = e; }
  float norm = 1.f / (p1 + p2 + 1e-8f);
  idx_pack[t] = e1 | (e2 << 8);
  p1o[t] = p1 * norm;
  p2o[t] = p2 * norm;
  for (int m = 1; m < 64; m <<= 1)
    for (int e = 0; e < EE; ++e) l[e] += __shfl_xor(l[e], m);
  if ((threadIdx.x & 63) == 0)
    for (int e = 0; e < EE; ++e) atomicAdd(&psum[e], l[e]);
}

__global__ __launch_bounds__(256) void k_route(
    const int* __restrict__ idx_pack, const float* __restrict__ p1,
    const float* __restrict__ p2, const float* __restrict__ psum,
    float* __restrict__ disp, float* __restrict__ comb, float* __restrict__ aux_out) {
  __shared__ int cnt[256][EE];
  __shared__ int tot[EE];
  int tid = threadIdx.x;
  const int CH = NASSIGN / 256;
  int n0 = tid * CH;
  int local[EE] = {};
  for (int n = n0; n < n0 + CH; ++n) {
    int t = n >> 1;
    int pk = idx_pack[t];
    int e = (n & 1) ? (pk >> 8) : (pk & 0xff);
    local[e]++;
  }
  for (int e = 0; e < EE; ++e) cnt[tid][e] = local[e];
  __syncthreads();
  if (tid < EE) {
    int run = 0;
    for (int t = 0; t < 256; ++t) { int v = cnt[t][tid]; cnt[t][tid] = run; run += v; }
    tot[tid] = run;
  }
  __syncthreads();
  int off[EE];
  for (int e = 0; e < EE; ++e) off[e] = cnt[tid][e];
  for (int n = n0; n < n0 + CH; ++n) {
    int t = n >> 1;
    int pk = idx_pack[t];
    int e; float p;
    if (n & 1) { e = pk >> 8; p = p2[t]; } else { e = pk & 0xff; p = p1[t]; }
    int pos = off[e]++;
    if (pos < CAP) {
      size_t o = (size_t)t * EE * CAP + (size_t)e * CAP + pos;
      disp[o] = 1.0f;
      comb[o] = p;
    }
  }
  if (tid == 0) {
    float aux = 0.f;
    for (int e = 0; e < EE; ++e)
      aux += (psum[e] / (float)NTOK) * ((float)tot[e] / (float)NASSIGN);
    aux_out[0] = aux * (float)EE;
  }
}

extern "C" void kernel_launch(void* const* d_in, const int* in_sizes, int n_in,
                              void* d_out, int out_size, void* d_ws, size_t ws_size,
                              hipStream_t stream) {
  const float* x   = (const float*)d_in[0];
  const float* w1  = (const float*)d_in[1];
  const float* b1  = (const float*)d_in[2];
  const float* w2  = (const float*)d_in[3];
  const float* b2  = (const float*)d_in[4];
  const float* wc1 = (const float*)d_in[5];
  const float* bc1 = (const float*)d_in[6];
  const float* wc2 = (const float*)d_in[7];
  const float* bc2 = (const float*)d_in[8];
  const float* chr = (const float*)d_in[9];

  float* out = (float*)d_out;
  float* disp  = out;
  float* comb  = disp + (size_t)NTOK * EE * CAP;
  float* probs = comb + (size_t)NTOK * EE * CAP;
  float* aux   = probs + (size_t)NTOK * EE;

  float* ws = (float*)d_ws;
  float* psum   = ws + WS_PSUM;
  float* hcr    = ws + WS_HC;
  float* adj    = ws + WS_ADJ;
  float* p1     = ws + WS_P1;
  float* p2     = ws + WS_P2;
  int*   idxp   = (int*)(ws + WS_IDX);
  float* logits = ws + WS_LOGITS;           // fallback only
  float* avgp   = ws + WS_LOGITS;           // avg partials (mfma + fallback pre-gemm)

  char* wsb = (char*)d_ws;
  unsigned short* Xh = (unsigned short*)(wsb + WS_BF16_BYTE);
  unsigned short* Xm = Xh + (size_t)NTOK * HH;
  unsigned short* Xl = Xm + (size_t)NTOK * HH;
  unsigned short* Wh = Xl + (size_t)NTOK * HH;
  unsigned short* Wm = Wh + (size_t)HH * HH;
  unsigned short* Wl = Wm + (size_t)HH * HH;
  float* lgz    = (float*)(wsb + WS_H_BYTE);            // mfma logits [4096][8]
  int*   posTab = (int*)(wsb + WS_H_BYTE + 131072);     // [4096][8]
  float* pTab   = (float*)(wsb + WS_H_BYTE + 262144);   // [4096][8]

  bool use_mfma = ws_size >= WS_NEED;

  if (use_mfma) {
    // D1: prep_x + prep_w + avg partials + ws-head & logits zero, one dispatch
    k_prep<<<PREPX_BLKS + PREPW_BLKS + AVG_BLKS, 256, 0, stream>>>(
        x, w1, Xh, Xm, Xl, Wh, Wm, Wl, ws, avgp, lgz);
    // D2: hc (atomics into hc_raw zeroed in D1)
    k_hc<<<dim3(HH / 256, 8, BB), 256, 0, stream>>>(avgp, chr, wc1, hcr);
    // D3: 2 adj blocks + 512 clean pipelined GEMM blocks (fused logits epi)
    k_fused<<<BB + NGEMM, 256, 0, stream>>>(
        Xh, Xm, Xl, Wh, Wm, Wl, b1, w2, hcr, bc1, wc2, bc2, adj, lgz);
    // D4: softmax + top2 + serial capacity -> posTab/pTab (+probs, aux)
    k_route2<<<1, 256, 0, stream>>>(lgz, b2, adj, probs, posTab, pTab, aux);
    // D5: dense streaming write of disp+comb (zeros + routed slots, one pass)
    k_write<<<NTOK, 256, 0, stream>>>(posTab, pTab, disp, comb);
  } else {
    hipMemsetAsync(d_ws, 0, WS_ZERO_BYTES, stream);
    hipMemsetAsync(d_out, 0, (size_t)out_size * sizeof(float), stream);
    k_avgp<<<dim3(HH / 256, 16, BB), 256, 0, stream>>>(x, avgp);
    k_hc<<<dim3(HH / 256, 8, BB), 256, 0, stream>>>(avgp, chr, wc1, hcr);
    k_adj<<<BB, 256, 0, stream>>>(hcr, bc1, wc2, bc2, adj);
    k_init_logits<<<(NTOK * EE) / 256, 256, 0, stream>>>(adj, b2, logits);
    k_gemm_f32<<<dim3(NTOK / 64, HH / 64), 256, 0, stream>>>(x, w1, b1, w2, logits);
    k_softmax<<<NTOK / 256, 256, 0, stream>>>(logits, probs, idxp, p1, p2, psum);
    k_route<<<1, 256, 0, stream>>>(idxp, p1, p2, psum, disp, comb, aux);
  }
}

// Round 4
// 618.536 us; speedup vs baseline: 1.1076x; 1.1076x over previous
//
#include <hip/hip_runtime.h>
#include <hip/hip_bf16.h>

#define BB 2
#define SS 2048
#define HH 1024
#define EE 8
#define KK 2
#define CAP 1536
#define NTOK (BB * SS)        // 4096
#define NASSIGN (NTOK * KK)   // 8192

// ---------------- workspace layout (float indices) ----------------
#define WS_PSUM   0            // 8
#define WS_AVG    8            // 2048  (fallback path full sums; unused in mfma path)
#define WS_HC     2056         // 2048  (raw pre-bias pre-relu, atomic target)
#define WS_ADJ    4104         // 16
#define WS_P1     4120         // 4096
#define WS_P2     8216         // 4096
#define WS_IDX    12312        // 4096 ints
#define WS_LOGITS 16408        // 32768: fallback logits OR avg partials (16*2*1024)
#define WS_ZERO_FLOATS 4112    // psum+avg+hc+adj head (zeroed by prep blk0 / memset)
#define WS_ZERO_BYTES 16448
#define WS_BF16_BYTE 196704    // bf16 planes start here (16B aligned)
// planes: Xh/Xm/Xl 3*8388608 B + Wh/Wm/Wl 3*2097152 B = 31457280 B
#define WS_H_BYTE (WS_BF16_BYTE + 31457280)   // mfma logits (131072 B used)
#define WS_NEED (WS_H_BYTE + 16777216ull)

using short8 = __attribute__((ext_vector_type(8))) short;
using u16x8  = __attribute__((ext_vector_type(8))) unsigned short;
using f32x4  = __attribute__((ext_vector_type(4))) float;

// ---- bf16 split helpers (manual RNE) ----
__device__ __forceinline__ unsigned short f2bf(float f) {
  unsigned u = __float_as_uint(f);
  unsigned r = (u + 0x7fffu + ((u >> 16) & 1u)) >> 16;
  return (unsigned short)r;
}
__device__ __forceinline__ float bf2f(unsigned short h) {
  return __uint_as_float((unsigned)h << 16);
}
__device__ __forceinline__ void split3(float x, unsigned short& h,
                                       unsigned short& m, unsigned short& l) {
  h = f2bf(x);
  float r = x - bf2f(h);
  m = f2bf(r);
  l = f2bf(r - bf2f(m));
}

// async global->LDS, 16B per lane; lptr is wave-uniform base, HW adds lane*16
__device__ __forceinline__ void gload_lds16(const void* g, void* l) {
  __builtin_amdgcn_global_load_lds(
      (const __attribute__((address_space(1))) void*)g,
      (__attribute__((address_space(3))) void*)l, 16, 0, 0);
}

// ---------------- D1: consolidated prep dispatch ----------------
// blocks [0,4096): split X -> bf16 planes (blk0 zeros ws scalar head,
//                  blks 1..32 zero the 32768-float logits buffer)
// blocks [4096,4352): split+transpose w1 -> bf16 planes
// blocks [4352,4480): avg partial sums (no atomics, no zero-init needed)
#define PREPX_BLKS 4096
#define PREPW_BLKS 256
#define AVG_BLKS   128
__global__ __launch_bounds__(256) void k_prep(
    const float* __restrict__ x, const float* __restrict__ w1,
    unsigned short* __restrict__ Xh, unsigned short* __restrict__ Xm,
    unsigned short* __restrict__ Xl,
    unsigned short* __restrict__ Wh, unsigned short* __restrict__ Wm,
    unsigned short* __restrict__ Wl,
    float* __restrict__ wshead, float* __restrict__ avg_part,
    float* __restrict__ lgz) {
  __shared__ unsigned short Th[64 * 65], Tm[64 * 65], Tl[64 * 65];
  int tid = threadIdx.x;
  int bid = blockIdx.x;
  if (bid < PREPX_BLKS) {
    if (bid == 0)
      for (int j = tid; j < WS_ZERO_FLOATS; j += 256) wshead[j] = 0.f;
    if (bid >= 1 && bid <= 32) {
      const float4 z = {0.f, 0.f, 0.f, 0.f};
      ((float4*)lgz)[(bid - 1) * 256 + tid] = z;   // zero 4096x8 logits
    }
    int i = (bid * 256 + tid) * 4;
    float4 v = *(const float4*)&x[i];
    unsigned short h[4], m[4], l[4];
    split3(v.x, h[0], m[0], l[0]);
    split3(v.y, h[1], m[1], l[1]);
    split3(v.z, h[2], m[2], l[2]);
    split3(v.w, h[3], m[3], l[3]);
    *(ushort4*)&Xh[i] = make_ushort4(h[0], h[1], h[2], h[3]);
    *(ushort4*)&Xm[i] = make_ushort4(m[0], m[1], m[2], m[3]);
    *(ushort4*)&Xl[i] = make_ushort4(l[0], l[1], l[2], l[3]);
  } else if (bid < PREPX_BLKS + PREPW_BLKS) {
    int pid = bid - PREPX_BLKS;
    int k0 = (pid & 15) * 64, n0 = (pid >> 4) * 64;
    for (int i = 0; i < 16; ++i) {
      int e = i * 256 + tid;
      int k = e >> 6, n = e & 63;
      float v = w1[(size_t)(k0 + k) * HH + n0 + n];
      unsigned short h, m, l;
      split3(v, h, m, l);
      Th[n * 65 + k] = h; Tm[n * 65 + k] = m; Tl[n * 65 + k] = l;
    }
    __syncthreads();
    for (int i = 0; i < 16; ++i) {
      int e = i * 256 + tid;
      int n = e >> 6, k = e & 63;
      size_t o = (size_t)(n0 + n) * HH + k0 + k;
      Wh[o] = Th[n * 65 + k]; Wm[o] = Tm[n * 65 + k]; Wl[o] = Tl[n * 65 + k];
    }
  } else {
    int pid = bid - PREPX_BLKS - PREPW_BLKS;  // 0..127
    int h = (pid & 3) * 256 + tid;
    int c = (pid >> 2) & 15;
    int b = pid >> 6;
    const float* p = x + (size_t)b * SS * HH + (size_t)(c * 128) * HH + h;
    float s = 0.f;
    for (int i = 0; i < 128; ++i) s += p[(size_t)i * HH];
    avg_part[(c * BB + b) * HH + h] = s;   // raw partial sum
  }
}

// standalone avg-partials kernel (fallback path only)
__global__ void k_avgp(const float* __restrict__ x, float* __restrict__ avg_part) {
  int h = blockIdx.x * 256 + threadIdx.x;
  int c = blockIdx.y;
  int b = blockIdx.z;
  const float* p = x + (size_t)b * SS * HH + (size_t)(c * 128) * HH + h;
  float s = 0.f;
  for (int i = 0; i < 128; ++i) s += p[(size_t)i * HH];
  avg_part[(c * BB + b) * HH + h] = s;
}

// hc_raw += partial dot over i-chunk; reduces the 16 avg partials through LDS
__global__ void k_hc(const float* __restrict__ avg_part, const float* __restrict__ chr,
                     const float* __restrict__ wc1, float* __restrict__ hc_raw) {
  __shared__ float avg_s[128];
  int tid = threadIdx.x;
  int j = blockIdx.x * 256 + tid;
  int c = blockIdx.y;
  int b = blockIdx.z;
  if (tid < 128) {
    float s = 0.f;
    for (int cc = 0; cc < 16; ++cc)
      s += avg_part[(cc * BB + b) * HH + c * 128 + tid];
    avg_s[tid] = s * (1.0f / SS);
  }
  __syncthreads();
  float acc = 0.f;
  for (int il = 0; il < 128; ++il)
    acc += avg_s[il] * wc1[(size_t)(c * 128 + il) * HH + j];
  if (c == 7)
    for (int i = 0; i < EE; ++i)
      acc += chr[i] * wc1[(size_t)(HH + i) * HH + j];
  atomicAdd(&hc_raw[b * HH + j], acc);
}

// standalone adj kernel (fallback path only; mfma path runs adj inside D3)
__global__ void k_adj(const float* __restrict__ hc_raw, const float* __restrict__ bc1,
                      const float* __restrict__ wc2, const float* __restrict__ bc2,
                      float* __restrict__ adj) {
  int b = blockIdx.x;
  int tid = threadIdx.x;
  float part[EE] = {};
  for (int j = tid; j < HH; j += 256) {
    float v = fmaxf(hc_raw[b * HH + j] + bc1[j], 0.f);
    for (int e = 0; e < EE; ++e) part[e] += v * wc2[j * EE + e];
  }
  for (int m = 1; m < 64; m <<= 1)
    for (int e = 0; e < EE; ++e) part[e] += __shfl_xor(part[e], m);
  __shared__ float red[4][EE];
  int wave = tid >> 6, lane = tid & 63;
  if (lane == 0)
    for (int e = 0; e < EE; ++e) red[wave][e] = part[e];
  __syncthreads();
  if (tid < EE) {
    float s = bc2[tid];
    for (int w = 0; w < 4; ++w) s += red[w][tid];
    adj[b * EE + tid] = tanhf(s);
  }
}

// ---------------- D3: fused dispatch (R0 loop structure) ----------------
// Grid = BB adj blocks + 512 GEMM blocks.
//  - GEMM: SINGLE-buffered K-loop, two barriers per K-step, ~39KB LDS
//    (4 blocks/CU capacity). This is the structure measured fast in R0;
//    the R1-R3 double-buffer (77KB LDS, 2 blocks/CU, same-iter drain of
//    its own prefetch) was 2x slower -- implicit cross-block overlap at
//    small LDS beats source-level pipelining here (m114/m132).
//  - In-loop NT zero stores of disp/comb (6/thread/iter), issued at the
//    top of the compute phase, drained at the NEXT iteration's 2nd barrier
//    (a full compute phase + 2 barriers of cover). Measured ~free in R0.
//  - LDS XOR swizzle (both-sides, rule #21): global-source k-quarter
//    permuted per lane, same involution on ds_read (4.7M -> 8K conflicts).
//  - Epilogue: relu(+b1), per-64col partial logits via w2 tile, atomicAdd
//    into logits (no hbuf round trip, no separate k_logits dispatch).
#define BM 128
#define BN 64
#define BK 32
#define NGEMM 512
#define ZF4_PER_BLOCK 49152   // 25165824 f4 (disp+comb) / 512
__global__ __launch_bounds__(256) void k_fused(
    const unsigned short* __restrict__ Xh, const unsigned short* __restrict__ Xm,
    const unsigned short* __restrict__ Xl,
    const unsigned short* __restrict__ Wh, const unsigned short* __restrict__ Wm,
    const unsigned short* __restrict__ Wl,
    const float* __restrict__ b1, const float* __restrict__ w2,
    f32x4* __restrict__ zout,
    const float* __restrict__ hc_raw, const float* __restrict__ bc1,
    const float* __restrict__ wc2, const float* __restrict__ bc2,
    float* __restrict__ adj, float* __restrict__ logits) {
  __shared__ unsigned short As[3][BM * BK];   // 24KB
  __shared__ unsigned short Bs[3][BN * BK];   // 12KB
  __shared__ float b1s[BN];
  __shared__ float w2s[BN * 9];               // padded stride 9
  __shared__ float red[4][EE];
  int tid = threadIdx.x;
  int bid = blockIdx.x;

  if (bid < BB) {  // ---- adj blocks ----
    int b = bid;
    float part[EE] = {};
    for (int j = tid; j < HH; j += 256) {
      float v = fmaxf(hc_raw[b * HH + j] + bc1[j], 0.f);
      for (int e = 0; e < EE; ++e) part[e] += v * wc2[j * EE + e];
    }
    for (int m = 1; m < 64; m <<= 1)
      for (int e = 0; e < EE; ++e) part[e] += __shfl_xor(part[e], m);
    int wave = tid >> 6, lane = tid & 63;
    if (lane == 0)
      for (int e = 0; e < EE; ++e) red[wave][e] = part[e];
    __syncthreads();
    if (tid < EE) {
      float s = bc2[tid];
      for (int w = 0; w < 4; ++w) s += red[w][tid];
      adj[b * EE + tid] = tanhf(s);
    }
    return;
  }

  // ---- GEMM blocks ----
  int g = bid - BB;                    // 0..511
  int gs = (g & 7) * 64 + (g >> 3);    // XCD-chunked swizzle (512 = 8*64)
  int m0 = (gs >> 4) * BM, n0 = (gs & 15) * BN;

  if (tid < BN) b1s[tid] = b1[n0 + tid];
#pragma unroll
  for (int rdx = 0; rdx < 2; ++rdx) {  // stage w2 tile: 64x8
    int i = tid + rdx * 256;
    int c = i >> 3, e = i & 7;
    w2s[c * 9 + e] = w2[(size_t)(n0 + c) * EE + e];
  }

  int lane = tid & 63, wave = tid >> 6;
  int wm = wave & 1, wn = wave >> 1;   // wave tile: 64 rows x 32 cols
  int q = lane >> 4, mr = lane & 15;
  // staging: row-within-group; k-quarter pre-swizzled at the GLOBAL source
  // (LDS dest stays linear for global_load_lds). Involution on read side.
  int lr = lane >> 2;
  int lqs = (lane & 3) ^ ((lane >> 3) & 3);
  // swizzled read quarter for this lane's fragment rows (row = mr)
  int qsw = (q ^ ((mr >> 1) & 3)) * 8;

  f32x4 acc[4][2] = {};
  const unsigned short* Ag[3] = {Xh, Xm, Xl};
  const unsigned short* Bg[3] = {Wh, Wm, Wl};

  f32x4* zp = zout + (size_t)g * ZF4_PER_BLOCK;
  const f32x4 z4 = {0.f, 0.f, 0.f, 0.f};

  for (int k0 = 0; k0 < HH; k0 += BK) {
    int t = k0 >> 5;
    __syncthreads();   // previous compute done; buffer reusable
    // A: 24 wave-instrs (3 planes x 8 groups of 16 rows); this wave does 6
#pragma unroll
    for (int j = 0; j < 6; ++j) {
      int i = wave + 4 * j;
      int s = i >> 3, gg = i & 7;
      gload_lds16(Ag[s] + (size_t)(m0 + gg * 16 + lr) * HH + k0 + lqs * 8,
                  &As[s][gg * 512]);
    }
    // B: 12 wave-instrs (3 planes x 4 groups of 16 rows); this wave does 3
#pragma unroll
    for (int j = 0; j < 3; ++j) {
      int i = wave + 4 * j;
      int s = i >> 2, gg = i & 3;
      gload_lds16(Bg[s] + (size_t)(n0 + gg * 16 + lr) * HH + k0 + lqs * 8,
                  &Bs[s][gg * 512]);
    }
    __syncthreads();   // staging loads complete

    // zero-fill slice: NT stores issued at the top of the compute phase,
    // drained at the NEXT iteration's 2nd barrier (full phase of cover).
    {
      f32x4* zb = zp + t * (256 * 6) + tid;
#pragma unroll
      for (int j = 0; j < 6; ++j) __builtin_nontemporal_store(z4, &zb[j * 256]);
    }

    short8 af[3][4], bv[3][2];
#pragma unroll
    for (int s = 0; s < 3; ++s) {
#pragma unroll
      for (int mi = 0; mi < 4; ++mi)
        af[s][mi] = *(const short8*)&As[s][(wm * 4 + mi) * 512 + mr * 32 + qsw];
#pragma unroll
      for (int ni = 0; ni < 2; ++ni)
        bv[s][ni] = *(const short8*)&Bs[s][(wn * 2 + ni) * 512 + mr * 32 + qsw];
    }
#pragma unroll
    for (int mi = 0; mi < 4; ++mi)
#pragma unroll
      for (int ni = 0; ni < 2; ++ni) {
        f32x4 c = acc[mi][ni];
        c = __builtin_amdgcn_mfma_f32_16x16x32_bf16(af[0][mi], bv[0][ni], c, 0, 0, 0); // h.h
        c = __builtin_amdgcn_mfma_f32_16x16x32_bf16(af[0][mi], bv[1][ni], c, 0, 0, 0); // h.m
        c = __builtin_amdgcn_mfma_f32_16x16x32_bf16(af[1][mi], bv[0][ni], c, 0, 0, 0); // m.h
        c = __builtin_amdgcn_mfma_f32_16x16x32_bf16(af[0][mi], bv[2][ni], c, 0, 0, 0); // h.l
        c = __builtin_amdgcn_mfma_f32_16x16x32_bf16(af[2][mi], bv[0][ni], c, 0, 0, 0); // l.h
        c = __builtin_amdgcn_mfma_f32_16x16x32_bf16(af[1][mi], bv[1][ni], c, 0, 0, 0); // m.m
        acc[mi][ni] = c;
      }
  }

  // epilogue: relu(+b1) then partial logits over this block's 64 cols.
  // lane holds rows (wm*64+mi*16+q*4+r), cols c0=wn*32+mr, c1=c0+16.
#pragma unroll
  for (int mi = 0; mi < 4; ++mi)
#pragma unroll
    for (int r = 0; r < 4; ++r) {
      int rowl = wm * 64 + mi * 16 + q * 4 + r;
      int c0 = wn * 32 + mr, c1 = c0 + 16;
      float v0 = fmaxf(acc[mi][0][r] + b1s[c0], 0.f);
      float v1 = fmaxf(acc[mi][1][r] + b1s[c1], 0.f);
      float pe[EE];
#pragma unroll
      for (int e = 0; e < EE; ++e)
        pe[e] = v0 * w2s[c0 * 9 + e] + v1 * w2s[c1 * 9 + e];
#pragma unroll
      for (int m = 1; m < 16; m <<= 1)
#pragma unroll
        for (int e = 0; e < EE; ++e) pe[e] += __shfl_xor(pe[e], m);
      if (mr == 0) {
        float* lp = &logits[(size_t)(m0 + rowl) * EE];
#pragma unroll
        for (int e = 0; e < EE; ++e) atomicAdd(&lp[e], pe[e]);
      }
    }
}

// ---------------- D4: fused softmax + top2 + serial capacity + scatter ----
// One block, 256 threads; thread tid owns tokens [tid*16, tid*16+16) =
// assignments [tid*32, +32) -- the reference's serial (b,s,k) order.
// disp/comb were pre-zeroed by k_fused's NT stores, so the scatter writes
// only the <=16K routed slots.
__global__ __launch_bounds__(256) void k_route2(
    const float* __restrict__ logits, const float* __restrict__ b2,
    const float* __restrict__ adj, float* __restrict__ probs_out,
    float* __restrict__ disp, float* __restrict__ comb,
    float* __restrict__ aux_out) {
  __shared__ int cnt[256][EE];   // 8KB
  __shared__ int tot[EE];
  __shared__ float psums[4][EE];
  int tid = threadIdx.x;
  int lane = tid & 63, wave = tid >> 6;

  float a0[EE], a1[EE], b2r[EE];
#pragma unroll
  for (int e = 0; e < EE; ++e) {
    b2r[e] = b2[e]; a0[e] = adj[e]; a1[e] = adj[EE + e];
  }

  int   myi[16];
  float myp1[16], myp2[16];
  int local[EE] = {};
  float psum_l[EE] = {};

#pragma unroll
  for (int i = 0; i < 16; ++i) {
    int t = tid * 16 + i;
    int hi = t >> 11;   // batch index
    float4 la = *(const float4*)&logits[(size_t)t * EE];
    float4 lb = *(const float4*)&logits[(size_t)t * EE + 4];
    float l[EE] = {la.x, la.y, la.z, la.w, lb.x, lb.y, lb.z, lb.w};
    float mx = -1e30f;
#pragma unroll
    for (int e = 0; e < EE; ++e) {
      float av = hi ? a1[e] : a0[e];
      l[e] += b2r[e] + av;          // same add order as before (bit-exact)
      mx = fmaxf(mx, l[e]);
    }
    float s = 0.f;
#pragma unroll
    for (int e = 0; e < EE; ++e) { l[e] = expf(l[e] - mx); s += l[e]; }
    float inv = 1.f / s;
#pragma unroll
    for (int e = 0; e < EE; ++e) { l[e] *= inv; psum_l[e] += l[e]; }
    float4 pa = {l[0], l[1], l[2], l[3]}, pb = {l[4], l[5], l[6], l[7]};
    *(float4*)&probs_out[(size_t)t * EE] = pa;
    *(float4*)&probs_out[(size_t)t * EE + 4] = pb;
    int e1 = 0; float p1 = l[0];
#pragma unroll
    for (int e = 1; e < EE; ++e) if (l[e] > p1) { p1 = l[e]; e1 = e; }
    int e2 = -1; float p2 = -1.f;
#pragma unroll
    for (int e = 0; e < EE; ++e) if (e != e1 && l[e] > p2) { p2 = l[e]; e2 = e; }
    float norm = 1.f / (p1 + p2 + 1e-8f);
    myi[i] = e1 | (e2 << 8);
    myp1[i] = p1 * norm;
    myp2[i] = p2 * norm;
    local[e1]++; local[e2]++;
  }

#pragma unroll
  for (int e = 0; e < EE; ++e) cnt[tid][e] = local[e];
  // psum wave+block reduce (feeds aux only)
#pragma unroll
  for (int m = 1; m < 64; m <<= 1)
#pragma unroll
    for (int e = 0; e < EE; ++e) psum_l[e] += __shfl_xor(psum_l[e], m);
  if (lane == 0)
#pragma unroll
    for (int e = 0; e < EE; ++e) psums[wave][e] = psum_l[e];
  __syncthreads();
  if (tid < EE) {
    int run = 0;
    for (int t = 0; t < 256; ++t) { int v = cnt[t][tid]; cnt[t][tid] = run; run += v; }
    tot[tid] = run;
  }
  __syncthreads();
  int off[EE];
#pragma unroll
  for (int e = 0; e < EE; ++e) off[e] = cnt[tid][e];

#pragma unroll
  for (int i = 0; i < 16; ++i) {
    int t = tid * 16 + i;
    int pk = myi[i];
    int e1 = pk & 0xff, e2 = pk >> 8;
    int pos1 = off[e1]++;          // assignment n = 2t   (uses p1)
    int pos2 = off[e2]++;          // assignment n = 2t+1 (uses p2)
    if (pos1 < CAP) {
      size_t o = (size_t)t * EE * CAP + (size_t)e1 * CAP + pos1;
      disp[o] = 1.0f;
      comb[o] = myp1[i];
    }
    if (pos2 < CAP) {
      size_t o = (size_t)t * EE * CAP + (size_t)e2 * CAP + pos2;
      disp[o] = 1.0f;
      comb[o] = myp2[i];
    }
  }

  if (tid == 0) {
    float aux = 0.f;
    for (int e = 0; e < EE; ++e) {
      float ps = psums[0][e] + psums[1][e] + psums[2][e] + psums[3][e];
      aux += (ps / (float)NTOK) * ((float)tot[e] / (float)NASSIGN);
    }
    aux_out[0] = aux * (float)EE;
  }
}

// ---------------- fp32 fallback GEMM (+ old softmax path) ----------------
__global__ __launch_bounds__(256) void k_gemm_f32(
    const float* __restrict__ X, const float* __restrict__ w1,
    const float* __restrict__ b1, const float* __restrict__ w2,
    float* __restrict__ logits) {
  __shared__ float Asf[16][65];
  __shared__ float Bsf[16][64];
  __shared__ float w2sf[64][EE];
  int tid = threadIdx.x;
  int m0 = blockIdx.x * 64, n0 = blockIdx.y * 64;
  for (int i = tid; i < 64 * EE; i += 256)
    w2sf[i / EE][i % EE] = w2[(size_t)(n0 + i / EE) * EE + (i % EE)];
  float acc[4][4] = {};
  int tx = tid & 15, ty = tid >> 4;
  for (int k0 = 0; k0 < HH; k0 += 16) {
    for (int idx = tid; idx < 64 * 16; idx += 256) {
      int m = idx >> 4, kk = idx & 15;
      Asf[kk][m] = X[(size_t)(m0 + m) * HH + k0 + kk];
    }
    for (int idx = tid; idx < 16 * 64; idx += 256) {
      int kk = idx >> 6, n = idx & 63;
      Bsf[kk][n] = w1[(size_t)(k0 + kk) * HH + n0 + n];
    }
    __syncthreads();
    for (int kk = 0; kk < 16; ++kk) {
      float a[4], bb[4];
      for (int i = 0; i < 4; ++i) a[i] = Asf[kk][ty * 4 + i];
      for (int j = 0; j < 4; ++j) bb[j] = Bsf[kk][tx * 4 + j];
      for (int i = 0; i < 4; ++i)
        for (int j = 0; j < 4; ++j) acc[i][j] += a[i] * bb[j];
    }
    __syncthreads();
  }
  float p[4][EE] = {};
  for (int i = 0; i < 4; ++i)
    for (int j = 0; j < 4; ++j) {
      int c = tx * 4 + j;
      float v = fmaxf(acc[i][j] + b1[n0 + c], 0.f);
      for (int e = 0; e < EE; ++e) p[i][e] += v * w2sf[c][e];
    }
  for (int m = 1; m < 16; m <<= 1)
    for (int i = 0; i < 4; ++i)
      for (int e = 0; e < EE; ++e) p[i][e] += __shfl_xor(p[i][e], m);
  if (tx == 0)
    for (int i = 0; i < 4; ++i)
      for (int e = 0; e < EE; ++e)
        atomicAdd(&logits[(size_t)(m0 + ty * 4 + i) * EE + e], p[i][e]);
}

__global__ void k_init_logits(const float* __restrict__ adj, const float* __restrict__ b2,
                              float* __restrict__ logits) {
  int i = blockIdx.x * 256 + threadIdx.x;
  int e = i & 7;
  int t = i >> 3;
  int b = t >> 11;
  logits[i] = b2[e] + adj[b * EE + e];
}

__global__ void k_softmax(const float* __restrict__ logits, float* __restrict__ probs_out,
                          int* __restrict__ idx_pack, float* __restrict__ p1o,
                          float* __restrict__ p2o, float* __restrict__ psum) {
  int t = blockIdx.x * 256 + threadIdx.x;
  float l[EE];
  float mx = -1e30f;
  for (int e = 0; e < EE; ++e) { l[e] = logits[t * EE + e]; mx = fmaxf(mx, l[e]); }
  float s = 0.f;
  for (int e = 0; e < EE; ++e) { l[e] = expf(l[e] - mx); s += l[e]; }
  float inv = 1.f / s;
  for (int e = 0; e < EE; ++e) { l[e] *= inv; probs_out[t * EE + e] = l[e]; }
  int e1 = 0; float p1 = l[0];
  for (int e = 1; e < EE; ++e) if (l[e] > p1) { p1 = l[e]; e1 = e; }
  int e2 = -1; float p2 = -1.f;
  for (int e = 0; e < EE; ++e) if (e != e1 && l[e] > p2) { p2 = l[e]; e2 = e; }
  float norm = 1.f / (p1 + p2 + 1e-8f);
  idx_pack[t] = e1 | (e2 << 8);
  p1o[t] = p1 * norm;
  p2o[t] = p2 * norm;
  for (int m = 1; m < 64; m <<= 1)
    for (int e = 0; e < EE; ++e) l[e] += __shfl_xor(l[e], m);
  if ((threadIdx.x & 63) == 0)
    for (int e = 0; e < EE; ++e) atomicAdd(&psum[e], l[e]);
}

__global__ __launch_bounds__(256) void k_route(
    const int* __restrict__ idx_pack, const float* __restrict__ p1,
    const float* __restrict__ p2, const float* __restrict__ psum,
    float* __restrict__ disp, float* __restrict__ comb, float* __restrict__ aux_out) {
  __shared__ int cnt[256][EE];
  __shared__ int tot[EE];
  int tid = threadIdx.x;
  const int CH = NASSIGN / 256;
  int n0 = tid * CH;
  int local[EE] = {};
  for (int n = n0; n < n0 + CH; ++n) {
    int t = n >> 1;
    int pk = idx_pack[t];
    int e = (n & 1) ? (pk >> 8) : (pk & 0xff);
    local[e]++;
  }
  for (int e = 0; e < EE; ++e) cnt[tid][e] = local[e];
  __syncthreads();
  if (tid < EE) {
    int run = 0;
    for (int t = 0; t < 256; ++t) { int v = cnt[t][tid]; cnt[t][tid] = run; run += v; }
    tot[tid] = run;
  }
  __syncthreads();
  int off[EE];
  for (int e = 0; e < EE; ++e) off[e] = cnt[tid][e];
  for (int n = n0; n < n0 + CH; ++n) {
    int t = n >> 1;
    int pk = idx_pack[t];
    int e; float p;
    if (n & 1) { e = pk >> 8; p = p2[t]; } else { e = pk & 0xff; p = p1[t]; }
    int pos = off[e]++;
    if (pos < CAP) {
      size_t o = (size_t)t * EE * CAP + (size_t)e * CAP + pos;
      disp[o] = 1.0f;
      comb[o] = p;
    }
  }
  if (tid == 0) {
    float aux = 0.f;
    for (int e = 0; e < EE; ++e)
      aux += (psum[e] / (float)NTOK) * ((float)tot[e] / (float)NASSIGN);
    aux_out[0] = aux * (float)EE;
  }
}

extern "C" void kernel_launch(void* const* d_in, const int* in_sizes, int n_in,
                              void* d_out, int out_size, void* d_ws, size_t ws_size,
                              hipStream_t stream) {
  const float* x   = (const float*)d_in[0];
  const float* w1  = (const float*)d_in[1];
  const float* b1  = (const float*)d_in[2];
  const float* w2  = (const float*)d_in[3];
  const float* b2  = (const float*)d_in[4];
  const float* wc1 = (const float*)d_in[5];
  const float* bc1 = (const float*)d_in[6];
  const float* wc2 = (const float*)d_in[7];
  const float* bc2 = (const float*)d_in[8];
  const float* chr = (const float*)d_in[9];

  float* out = (float*)d_out;
  float* disp  = out;
  float* comb  = disp + (size_t)NTOK * EE * CAP;
  float* probs = comb + (size_t)NTOK * EE * CAP;
  float* aux   = probs + (size_t)NTOK * EE;

  float* ws = (float*)d_ws;
  float* psum   = ws + WS_PSUM;
  float* hcr    = ws + WS_HC;
  float* adj    = ws + WS_ADJ;
  float* p1     = ws + WS_P1;
  float* p2     = ws + WS_P2;
  int*   idxp   = (int*)(ws + WS_IDX);
  float* logits = ws + WS_LOGITS;           // fallback only
  float* avgp   = ws + WS_LOGITS;           // avg partials (mfma + fallback pre-gemm)

  char* wsb = (char*)d_ws;
  unsigned short* Xh = (unsigned short*)(wsb + WS_BF16_BYTE);
  unsigned short* Xm = Xh + (size_t)NTOK * HH;
  unsigned short* Xl = Xm + (size_t)NTOK * HH;
  unsigned short* Wh = Xl + (size_t)NTOK * HH;
  unsigned short* Wm = Wh + (size_t)HH * HH;
  unsigned short* Wl = Wm + (size_t)HH * HH;
  float* lgz = (float*)(wsb + WS_H_BYTE);   // mfma logits [4096][8]

  bool use_mfma = ws_size >= WS_NEED;

  if (use_mfma) {
    // D1: prep_x + prep_w + avg partials + ws-head & logits zero, one dispatch
    k_prep<<<PREPX_BLKS + PREPW_BLKS + AVG_BLKS, 256, 0, stream>>>(
        x, w1, Xh, Xm, Xl, Wh, Wm, Wl, ws, avgp, lgz);
    // D2: hc (atomics into hc_raw zeroed in D1)
    k_hc<<<dim3(HH / 256, 8, BB), 256, 0, stream>>>(avgp, chr, wc1, hcr);
    // D3: 2 adj blocks + 512 single-buffered GEMM blocks (in-loop NT zeroing
    //     of disp/comb; fused w2-logits epilogue)
    k_fused<<<BB + NGEMM, 256, 0, stream>>>(
        Xh, Xm, Xl, Wh, Wm, Wl, b1, w2, (f32x4*)d_out,
        hcr, bc1, wc2, bc2, adj, lgz);
    // D4: softmax + top2 + serial capacity + direct scatter (+probs, aux)
    k_route2<<<1, 256, 0, stream>>>(lgz, b2, adj, probs, disp, comb, aux);
  } else {
    hipMemsetAsync(d_ws, 0, WS_ZERO_BYTES, stream);
    hipMemsetAsync(d_out, 0, (size_t)out_size * sizeof(float), stream);
    k_avgp<<<dim3(HH / 256, 16, BB), 256, 0, stream>>>(x, avgp);
    k_hc<<<dim3(HH / 256, 8, BB), 256, 0, stream>>>(avgp, chr, wc1, hcr);
    k_adj<<<BB, 256, 0, stream>>>(hcr, bc1, wc2, bc2, adj);
    k_init_logits<<<(NTOK * EE) / 256, 256, 0, stream>>>(adj, b2, logits);
    k_gemm_f32<<<dim3(NTOK / 64, HH / 64), 256, 0, stream>>>(x, w1, b1, w2, logits);
    k_softmax<<<NTOK / 256, 256, 0, stream>>>(logits, probs, idxp, p1, p2, psum);
    k_route<<<1, 256, 0, stream>>>(idxp, p1, p2, psum, disp, comb, aux);
  }
}

// Round 6
// 504.488 us; speedup vs baseline: 1.3580x; 1.2261x over previous
//
#include <hip/hip_runtime.h>
#include <hip/hip_bf16.h>

#define BB 2
#define SS 2048
#define HH 1024
#define EE 8
#define KK 2
#define CAP 1536
#define NTOK (BB * SS)        // 4096
#define NASSIGN (NTOK * KK)   // 8192

// ---------------- workspace layout (float indices) ----------------
#define WS_PSUM   0            // 8
#define WS_AVG    8            // 2048  (fallback path full sums; unused in mfma path)
#define WS_HC     2056         // 2048  (raw pre-bias pre-relu, atomic target)
#define WS_ADJ    4104         // 16
#define WS_P1     4120         // 4096
#define WS_P2     8216         // 4096
#define WS_IDX    12312        // 4096 ints
#define WS_LOGITS 16408        // 32768: fallback logits OR avg partials (16*2*1024)
#define WS_ZERO_FLOATS 4112    // psum+avg+hc+adj head (zeroed by prep blk0 / memset)
#define WS_ZERO_BYTES 16448
#define WS_BF16_BYTE 196704    // bf16 planes start here (16B aligned)
// planes: Xh/Xm/Xl 3*8388608 B + Wh/Wm/Wl 3*2097152 B = 31457280 B
#define WS_H_BYTE (WS_BF16_BYTE + 31457280)   // plg partial logits (4MB used)
#define WS_NEED (WS_H_BYTE + 16777216ull)

using short8 = __attribute__((ext_vector_type(8))) short;
using u16x8  = __attribute__((ext_vector_type(8))) unsigned short;
using f32x4  = __attribute__((ext_vector_type(4))) float;

// ---- bf16 split helpers (manual RNE) ----
__device__ __forceinline__ unsigned short f2bf(float f) {
  unsigned u = __float_as_uint(f);
  unsigned r = (u + 0x7fffu + ((u >> 16) & 1u)) >> 16;
  return (unsigned short)r;
}
__device__ __forceinline__ float bf2f(unsigned short h) {
  return __uint_as_float((unsigned)h << 16);
}
__device__ __forceinline__ void split3(float x, unsigned short& h,
                                       unsigned short& m, unsigned short& l) {
  h = f2bf(x);
  float r = x - bf2f(h);
  m = f2bf(r);
  l = f2bf(r - bf2f(m));
}

// async global->LDS, 16B per lane; lptr is wave-uniform base, HW adds lane*16
__device__ __forceinline__ void gload_lds16(const void* g, void* l) {
  __builtin_amdgcn_global_load_lds(
      (const __attribute__((address_space(1))) void*)g,
      (__attribute__((address_space(3))) void*)l, 16, 0, 0);
}

// ---------------- D1: consolidated prep dispatch ----------------
// blocks [0,4096): split X -> bf16 planes (blk0 also zeros ws scalar head)
// blocks [4096,4352): split+transpose w1 -> bf16 planes
// blocks [4352,4480): avg partial sums (no atomics, no zero-init needed)
#define PREPX_BLKS 4096
#define PREPW_BLKS 256
#define AVG_BLKS   128
__global__ __launch_bounds__(256) void k_prep(
    const float* __restrict__ x, const float* __restrict__ w1,
    unsigned short* __restrict__ Xh, unsigned short* __restrict__ Xm,
    unsigned short* __restrict__ Xl,
    unsigned short* __restrict__ Wh, unsigned short* __restrict__ Wm,
    unsigned short* __restrict__ Wl,
    float* __restrict__ wshead, float* __restrict__ avg_part) {
  __shared__ unsigned short Th[64 * 65], Tm[64 * 65], Tl[64 * 65];
  int tid = threadIdx.x;
  int bid = blockIdx.x;
  if (bid < PREPX_BLKS) {
    if (bid == 0)
      for (int j = tid; j < WS_ZERO_FLOATS; j += 256) wshead[j] = 0.f;
    int i = (bid * 256 + tid) * 4;
    float4 v = *(const float4*)&x[i];
    unsigned short h[4], m[4], l[4];
    split3(v.x, h[0], m[0], l[0]);
    split3(v.y, h[1], m[1], l[1]);
    split3(v.z, h[2], m[2], l[2]);
    split3(v.w, h[3], m[3], l[3]);
    *(ushort4*)&Xh[i] = make_ushort4(h[0], h[1], h[2], h[3]);
    *(ushort4*)&Xm[i] = make_ushort4(m[0], m[1], m[2], m[3]);
    *(ushort4*)&Xl[i] = make_ushort4(l[0], l[1], l[2], l[3]);
  } else if (bid < PREPX_BLKS + PREPW_BLKS) {
    int pid = bid - PREPX_BLKS;
    int k0 = (pid & 15) * 64, n0 = (pid >> 4) * 64;
    for (int i = 0; i < 16; ++i) {
      int e = i * 256 + tid;
      int k = e >> 6, n = e & 63;
      float v = w1[(size_t)(k0 + k) * HH + n0 + n];
      unsigned short h, m, l;
      split3(v, h, m, l);
      Th[n * 65 + k] = h; Tm[n * 65 + k] = m; Tl[n * 65 + k] = l;
    }
    __syncthreads();
    for (int i = 0; i < 16; ++i) {
      int e = i * 256 + tid;
      int n = e >> 6, k = e & 63;
      size_t o = (size_t)(n0 + n) * HH + k0 + k;
      Wh[o] = Th[n * 65 + k]; Wm[o] = Tm[n * 65 + k]; Wl[o] = Tl[n * 65 + k];
    }
  } else {
    int pid = bid - PREPX_BLKS - PREPW_BLKS;  // 0..127
    int h = (pid & 3) * 256 + tid;
    int c = (pid >> 2) & 15;
    int b = pid >> 6;
    const float* p = x + (size_t)b * SS * HH + (size_t)(c * 128) * HH + h;
    float s = 0.f;
    for (int i = 0; i < 128; ++i) s += p[(size_t)i * HH];
    avg_part[(c * BB + b) * HH + h] = s;   // raw partial sum
  }
}

// standalone avg-partials kernel (fallback path only)
__global__ void k_avgp(const float* __restrict__ x, float* __restrict__ avg_part) {
  int h = blockIdx.x * 256 + threadIdx.x;
  int c = blockIdx.y;
  int b = blockIdx.z;
  const float* p = x + (size_t)b * SS * HH + (size_t)(c * 128) * HH + h;
  float s = 0.f;
  for (int i = 0; i < 128; ++i) s += p[(size_t)i * HH];
  avg_part[(c * BB + b) * HH + h] = s;
}

// hc_raw += partial dot over i-chunk; reduces the 16 avg partials through LDS
__global__ void k_hc(const float* __restrict__ avg_part, const float* __restrict__ chr,
                     const float* __restrict__ wc1, float* __restrict__ hc_raw) {
  __shared__ float avg_s[128];
  int tid = threadIdx.x;
  int j = blockIdx.x * 256 + tid;
  int c = blockIdx.y;
  int b = blockIdx.z;
  if (tid < 128) {
    float s = 0.f;
    for (int cc = 0; cc < 16; ++cc)
      s += avg_part[(cc * BB + b) * HH + c * 128 + tid];
    avg_s[tid] = s * (1.0f / SS);
  }
  __syncthreads();
  float acc = 0.f;
  for (int il = 0; il < 128; ++il)
    acc += avg_s[il] * wc1[(size_t)(c * 128 + il) * HH + j];
  if (c == 7)
    for (int i = 0; i < EE; ++i)
      acc += chr[i] * wc1[(size_t)(HH + i) * HH + j];
  atomicAdd(&hc_raw[b * HH + j], acc);
}

// standalone adj kernel (fallback path only; mfma path runs adj inside D3)
__global__ void k_adj(const float* __restrict__ hc_raw, const float* __restrict__ bc1,
                      const float* __restrict__ wc2, const float* __restrict__ bc2,
                      float* __restrict__ adj) {
  int b = blockIdx.x;
  int tid = threadIdx.x;
  float part[EE] = {};
  for (int j = tid; j < HH; j += 256) {
    float v = fmaxf(hc_raw[b * HH + j] + bc1[j], 0.f);
    for (int e = 0; e < EE; ++e) part[e] += v * wc2[j * EE + e];
  }
  for (int m = 1; m < 64; m <<= 1)
    for (int e = 0; e < EE; ++e) part[e] += __shfl_xor(part[e], m);
  __shared__ float red[4][EE];
  int wave = tid >> 6, lane = tid & 63;
  if (lane == 0)
    for (int e = 0; e < EE; ++e) red[wave][e] = part[e];
  __syncthreads();
  if (tid < EE) {
    float s = bc2[tid];
    for (int w = 0; w < 4; ++w) s += red[w][tid];
    adj[b * EE + tid] = tanhf(s);
  }
}

// ---------------- D3: MFMA GEMM (R0 structure, verified deltas only) -----
// Grid (32,17): y<16 -> GEMM blocks, each also NT-zeroes a 786KB slice of
// disp/comb from inside the compute phase (R0 mechanism, measured fast).
// y==16, x<2 -> adj blocks.
// Verified deltas vs R0:
//  - both-sides LDS swizzle (source k-quarter permute + same involution on
//    ds_read): bank conflicts 4.7M -> 8K [measured R2-R4].
//  - epilogue computes per-wave partial logits over that wave's 32 cols and
//    stores them (plain stores, no atomics) to plg[slice][row][8] where
//    slice = blockIdx.y*2 + wn. R5 BUG FIX: the two wn-waves of a block
//    cover different 32-col halves of the same rows -- they must write
//    DIFFERENT slices (R5 had them racing on one slice -> absmax 1.0).
#define BM 128
#define BN 64
#define BK 32
#define NSLICE 32             // (HH/BN) * 2 wn-waves
#define ZF4_PER_BLOCK 49152   // 25165824 f4 (disp+comb) / 512 gemm blocks
__global__ __launch_bounds__(256) void k_gemm_mfma(
    const unsigned short* __restrict__ Xh, const unsigned short* __restrict__ Xm,
    const unsigned short* __restrict__ Xl,
    const unsigned short* __restrict__ Wh, const unsigned short* __restrict__ Wm,
    const unsigned short* __restrict__ Wl,
    const float* __restrict__ b1, const float* __restrict__ w2,
    float* __restrict__ plg,
    f32x4* __restrict__ zout,
    const float* __restrict__ hc_raw, const float* __restrict__ bc1,
    const float* __restrict__ wc2, const float* __restrict__ bc2,
    float* __restrict__ adj) {
  __shared__ unsigned short As[3][BM * BK];   // 24KB
  __shared__ unsigned short Bs[3][BN * BK];   // 12KB
  __shared__ float b1s[BN];
  __shared__ float w2s[BN * 9];               // padded stride 9
  __shared__ float red[4][EE];
  int tid = threadIdx.x;

  if (blockIdx.y == HH / BN) {   // adj blocks
    if (blockIdx.x >= BB) return;
    int b = blockIdx.x;
    float part[EE] = {};
    for (int j = tid; j < HH; j += 256) {
      float v = fmaxf(hc_raw[b * HH + j] + bc1[j], 0.f);
      for (int e = 0; e < EE; ++e) part[e] += v * wc2[j * EE + e];
    }
    for (int m = 1; m < 64; m <<= 1)
      for (int e = 0; e < EE; ++e) part[e] += __shfl_xor(part[e], m);
    int wave = tid >> 6, lane = tid & 63;
    if (lane == 0)
      for (int e = 0; e < EE; ++e) red[wave][e] = part[e];
    __syncthreads();
    if (tid < EE) {
      float s = bc2[tid];
      for (int w = 0; w < 4; ++w) s += red[w][tid];
      adj[b * EE + tid] = tanhf(s);
    }
    return;
  }

  int m0 = blockIdx.x * BM, n0 = blockIdx.y * BN;
  if (tid < BN) b1s[tid] = b1[n0 + tid];
#pragma unroll
  for (int rdx = 0; rdx < 2; ++rdx) {  // stage w2 tile: 64x8
    int i = tid + rdx * 256;
    int c = i >> 3, e = i & 7;
    w2s[c * 9 + e] = w2[(size_t)(n0 + c) * EE + e];
  }

  int bid = blockIdx.y * gridDim.x + blockIdx.x;   // 0..511
  f32x4* zp = zout + (size_t)bid * ZF4_PER_BLOCK;
  const f32x4 z4 = {0.f, 0.f, 0.f, 0.f};

  int lane = tid & 63, wave = tid >> 6;
  int wm = wave & 1, wn = wave >> 1;   // wave tile: 64 rows x 32 cols
  int q = lane >> 4, mr = lane & 15;
  // staging: row-within-group; k-quarter pre-swizzled at the GLOBAL source
  // (LDS dest stays linear for global_load_lds); same involution on read.
  int lr = lane >> 2;
  int lqs = (lane & 3) ^ ((lane >> 3) & 3);
  int qsw = (q ^ ((mr >> 1) & 3)) * 8;

  f32x4 acc[4][2] = {};
  const unsigned short* Ag[3] = {Xh, Xm, Xl};
  const unsigned short* Bg[3] = {Wh, Wm, Wl};

  for (int k0 = 0; k0 < HH; k0 += BK) {
    __syncthreads();
    // A: 24 wave-instrs (3 planes x 8 groups of 16 rows); this wave does 6
#pragma unroll
    for (int j = 0; j < 6; ++j) {
      int i = wave + 4 * j;
      int s = i >> 3, g = i & 7;
      gload_lds16(Ag[s] + (size_t)(m0 + g * 16 + lr) * HH + k0 + lqs * 8,
                  &As[s][g * 512]);
    }
    // B: 12 wave-instrs (3 planes x 4 groups of 16 rows); this wave does 3
#pragma unroll
    for (int j = 0; j < 3; ++j) {
      int i = wave + 4 * j;
      int s = i >> 2, g = i & 3;
      gload_lds16(Bg[s] + (size_t)(n0 + g * 16 + lr) * HH + k0 + lqs * 8,
                  &Bs[s][g * 512]);
    }
    __syncthreads();

    // zero-fill slice: NT stores issued at the top of the compute phase,
    // drain during MFMA (R0 mechanism, measured ~free).
    {
      int ki = k0 >> 5;
      f32x4* zb = zp + ki * (256 * 6) + tid;
#pragma unroll
      for (int j = 0; j < 6; ++j) __builtin_nontemporal_store(z4, &zb[j * 256]);
    }

    short8 af[3][4], bv[3][2];
#pragma unroll
    for (int s = 0; s < 3; ++s) {
#pragma unroll
      for (int mi = 0; mi < 4; ++mi)
        af[s][mi] = *(const short8*)&As[s][(wm * 4 + mi) * 512 + mr * 32 + qsw];
#pragma unroll
      for (int ni = 0; ni < 2; ++ni)
        bv[s][ni] = *(const short8*)&Bs[s][(wn * 2 + ni) * 512 + mr * 32 + qsw];
    }
#pragma unroll
    for (int mi = 0; mi < 4; ++mi)
#pragma unroll
      for (int ni = 0; ni < 2; ++ni) {
        f32x4 c = acc[mi][ni];
        c = __builtin_amdgcn_mfma_f32_16x16x32_bf16(af[0][mi], bv[0][ni], c, 0, 0, 0); // h.h
        c = __builtin_amdgcn_mfma_f32_16x16x32_bf16(af[0][mi], bv[1][ni], c, 0, 0, 0); // h.m
        c = __builtin_amdgcn_mfma_f32_16x16x32_bf16(af[1][mi], bv[0][ni], c, 0, 0, 0); // m.h
        c = __builtin_amdgcn_mfma_f32_16x16x32_bf16(af[0][mi], bv[2][ni], c, 0, 0, 0); // h.l
        c = __builtin_amdgcn_mfma_f32_16x16x32_bf16(af[2][mi], bv[0][ni], c, 0, 0, 0); // l.h
        c = __builtin_amdgcn_mfma_f32_16x16x32_bf16(af[1][mi], bv[1][ni], c, 0, 0, 0); // m.m
        acc[mi][ni] = c;
      }
  }

  // epilogue: relu(+b1), then this wave's partial logits over its 32 cols.
  // lane holds rows (wm*64+mi*16+q*4+r), cols c0=wn*32+mr, c1=c0+16.
  // shfl_xor m<16 reduces over mr (16 lanes); mr==0 lane stores 8 floats.
  // slice = blockIdx.y*2 + wn: each (row, slice) written by exactly one lane.
  int slice = blockIdx.y * 2 + wn;   // 0..31
#pragma unroll
  for (int mi = 0; mi < 4; ++mi)
#pragma unroll
    for (int r = 0; r < 4; ++r) {
      int rowl = wm * 64 + mi * 16 + q * 4 + r;
      int c0 = wn * 32 + mr, c1 = c0 + 16;
      float v0 = fmaxf(acc[mi][0][r] + b1s[c0], 0.f);
      float v1 = fmaxf(acc[mi][1][r] + b1s[c1], 0.f);
      float pe[EE];
#pragma unroll
      for (int e = 0; e < EE; ++e)
        pe[e] = v0 * w2s[c0 * 9 + e] + v1 * w2s[c1 * 9 + e];
#pragma unroll
      for (int m = 1; m < 16; m <<= 1)
#pragma unroll
        for (int e = 0; e < EE; ++e) pe[e] += __shfl_xor(pe[e], m);
      if (mr == 0) {
        float* lp = &plg[((size_t)slice * NTOK + (m0 + rowl)) * EE];
        float4 pa = {pe[0], pe[1], pe[2], pe[3]};
        float4 pb = {pe[4], pe[5], pe[6], pe[7]};
        *(float4*)lp = pa;
        *(float4*)(lp + 4) = pb;
      }
    }
}

// ---------------- D4: sum plg slices + softmax + top2 + psum ------------
// 16 blocks x 256 threads, one token per thread. Reads the 32 partial-logit
// slices (4MB, coalesced 32B/thread/slice), finishes logits with b2+adj,
// then softmax / top-2 / normalization / psum exactly like R0's k_logits.
__global__ __launch_bounds__(256) void k_logits2(
    const float* __restrict__ plg, const float* __restrict__ b2,
    const float* __restrict__ adj, float* __restrict__ probs_out,
    int* __restrict__ idx_pack, float* __restrict__ p1o, float* __restrict__ p2o,
    float* __restrict__ psum) {
  __shared__ float ps[EE];
  int tid = threadIdx.x;
  if (tid < EE) ps[tid] = 0.f;
  __syncthreads();
  int t = blockIdx.x * 256 + tid;
  int b = t >> 11;
  float l[EE] = {};
#pragma unroll
  for (int s = 0; s < NSLICE; ++s) {
    const float* pp = &plg[((size_t)s * NTOK + t) * EE];
    float4 a = *(const float4*)pp;
    float4 c = *(const float4*)(pp + 4);
    l[0] += a.x; l[1] += a.y; l[2] += a.z; l[3] += a.w;
    l[4] += c.x; l[5] += c.y; l[6] += c.z; l[7] += c.w;
  }
  float mx = -1e30f;
#pragma unroll
  for (int e = 0; e < EE; ++e) {
    l[e] += b2[e] + adj[b * EE + e];
    mx = fmaxf(mx, l[e]);
  }
  float s = 0.f;
#pragma unroll
  for (int e = 0; e < EE; ++e) { l[e] = expf(l[e] - mx); s += l[e]; }
  float inv = 1.f / s;
#pragma unroll
  for (int e = 0; e < EE; ++e) l[e] *= inv;
  float4 pa = {l[0], l[1], l[2], l[3]}, pb = {l[4], l[5], l[6], l[7]};
  *(float4*)&probs_out[(size_t)t * EE] = pa;
  *(float4*)&probs_out[(size_t)t * EE + 4] = pb;
  int e1 = 0; float p1 = l[0];
#pragma unroll
  for (int e = 1; e < EE; ++e) if (l[e] > p1) { p1 = l[e]; e1 = e; }
  int e2 = -1; float p2 = -1.f;
#pragma unroll
  for (int e = 0; e < EE; ++e) if (e != e1 && l[e] > p2) { p2 = l[e]; e2 = e; }
  float norm = 1.f / (p1 + p2 + 1e-8f);
  idx_pack[t] = e1 | (e2 << 8);
  p1o[t] = p1 * norm;
  p2o[t] = p2 * norm;
#pragma unroll
  for (int m = 1; m < 64; m <<= 1)
#pragma unroll
    for (int e = 0; e < EE; ++e) l[e] += __shfl_xor(l[e], m);
  if ((tid & 63) == 0)
#pragma unroll
    for (int e = 0; e < EE; ++e) atomicAdd(&ps[e], l[e]);
  __syncthreads();
  if (tid < EE) atomicAdd(&psum[tid], ps[tid]);
}

// ---------------- fp32 fallback GEMM (+ old softmax path) ----------------
__global__ __launch_bounds__(256) void k_gemm_f32(
    const float* __restrict__ X, const float* __restrict__ w1,
    const float* __restrict__ b1, const float* __restrict__ w2,
    float* __restrict__ logits) {
  __shared__ float Asf[16][65];
  __shared__ float Bsf[16][64];
  __shared__ float w2sf[64][EE];
  int tid = threadIdx.x;
  int m0 = blockIdx.x * 64, n0 = blockIdx.y * 64;
  for (int i = tid; i < 64 * EE; i += 256)
    w2sf[i / EE][i % EE] = w2[(size_t)(n0 + i / EE) * EE + (i % EE)];
  float acc[4][4] = {};
  int tx = tid & 15, ty = tid >> 4;
  for (int k0 = 0; k0 < HH; k0 += 16) {
    for (int idx = tid; idx < 64 * 16; idx += 256) {
      int m = idx >> 4, kk = idx & 15;
      Asf[kk][m] = X[(size_t)(m0 + m) * HH + k0 + kk];
    }
    for (int idx = tid; idx < 16 * 64; idx += 256) {
      int kk = idx >> 6, n = idx & 63;
      Bsf[kk][n] = w1[(size_t)(k0 + kk) * HH + n0 + n];
    }
    __syncthreads();
    for (int kk = 0; kk < 16; ++kk) {
      float a[4], bb[4];
      for (int i = 0; i < 4; ++i) a[i] = Asf[kk][ty * 4 + i];
      for (int j = 0; j < 4; ++j) bb[j] = Bsf[kk][tx * 4 + j];
      for (int i = 0; i < 4; ++i)
        for (int j = 0; j < 4; ++j) acc[i][j] += a[i] * bb[j];
    }
    __syncthreads();
  }
  float p[4][EE] = {};
  for (int i = 0; i < 4; ++i)
    for (int j = 0; j < 4; ++j) {
      int c = tx * 4 + j;
      float v = fmaxf(acc[i][j] + b1[n0 + c], 0.f);
      for (int e = 0; e < EE; ++e) p[i][e] += v * w2sf[c][e];
    }
  for (int m = 1; m < 16; m <<= 1)
    for (int i = 0; i < 4; ++i)
      for (int e = 0; e < EE; ++e) p[i][e] += __shfl_xor(p[i][e], m);
  if (tx == 0)
    for (int i = 0; i < 4; ++i)
      for (int e = 0; e < EE; ++e)
        atomicAdd(&logits[(size_t)(m0 + ty * 4 + i) * EE + e], p[i][e]);
}

__global__ void k_init_logits(const float* __restrict__ adj, const float* __restrict__ b2,
                              float* __restrict__ logits) {
  int i = blockIdx.x * 256 + threadIdx.x;
  int e = i & 7;
  int t = i >> 3;
  int b = t >> 11;
  logits[i] = b2[e] + adj[b * EE + e];
}

__global__ void k_softmax(const float* __restrict__ logits, float* __restrict__ probs_out,
                          int* __restrict__ idx_pack, float* __restrict__ p1o,
                          float* __restrict__ p2o, float* __restrict__ psum) {
  int t = blockIdx.x * 256 + threadIdx.x;
  float l[EE];
  float mx = -1e30f;
  for (int e = 0; e < EE; ++e) { l[e] = logits[t * EE + e]; mx = fmaxf(mx, l[e]); }
  float s = 0.f;
  for (int e = 0; e < EE; ++e) { l[e] = expf(l[e] - mx); s += l[e]; }
  float inv = 1.f / s;
  for (int e = 0; e < EE; ++e) { l[e] *= inv; probs_out[t * EE + e] = l[e]; }
  int e1 = 0; float p1 = l[0];
  for (int e = 1; e < EE; ++e) if (l[e] > p1) { p1 = l[e]; e1 = e; }
  int e2 = -1; float p2 = -1.f;
  for (int e = 0; e < EE; ++e) if (e != e1 && l[e] > p2) { p2 = l[e]; e2 = e; }
  float norm = 1.f / (p1 + p2 + 1e-8f);
  idx_pack[t] = e1 | (e2 << 8);
  p1o[t] = p1 * norm;
  p2o[t] = p2 * norm;
  for (int m = 1; m < 64; m <<= 1)
    for (int e = 0; e < EE; ++e) l[e] += __shfl_xor(l[e], m);
  if ((threadIdx.x & 63) == 0)
    for (int e = 0; e < EE; ++e) atomicAdd(&psum[e], l[e]);
}

__global__ __launch_bounds__(256) void k_route(
    const int* __restrict__ idx_pack, const float* __restrict__ p1,
    const float* __restrict__ p2, const float* __restrict__ psum,
    float* __restrict__ disp, float* __restrict__ comb, float* __restrict__ aux_out) {
  __shared__ int cnt[256][EE];
  __shared__ int tot[EE];
  int tid = threadIdx.x;
  const int CH = NASSIGN / 256;
  int n0 = tid * CH;
  int local[EE] = {};
  for (int n = n0; n < n0 + CH; ++n) {
    int t = n >> 1;
    int pk = idx_pack[t];
    int e = (n & 1) ? (pk >> 8) : (pk & 0xff);
    local[e]++;
  }
  for (int e = 0; e < EE; ++e) cnt[tid][e] = local[e];
  __syncthreads();
  if (tid < EE) {
    int run = 0;
    for (int t = 0; t < 256; ++t) { int v = cnt[t][tid]; cnt[t][tid] = run; run += v; }
    tot[tid] = run;
  }
  __syncthreads();
  int off[EE];
  for (int e = 0; e < EE; ++e) off[e] = cnt[tid][e];
  for (int n = n0; n < n0 + CH; ++n) {
    int t = n >> 1;
    int pk = idx_pack[t];
    int e; float p;
    if (n & 1) { e = pk >> 8; p = p2[t]; } else { e = pk & 0xff; p = p1[t]; }
    int pos = off[e]++;
    if (pos < CAP) {
      size_t o = (size_t)t * EE * CAP + (size_t)e * CAP + pos;
      disp[o] = 1.0f;
      comb[o] = p;
    }
  }
  if (tid == 0) {
    float aux = 0.f;
    for (int e = 0; e < EE; ++e)
      aux += (psum[e] / (float)NTOK) * ((float)tot[e] / (float)NASSIGN);
    aux_out[0] = aux * (float)EE;
  }
}

extern "C" void kernel_launch(void* const* d_in, const int* in_sizes, int n_in,
                              void* d_out, int out_size, void* d_ws, size_t ws_size,
                              hipStream_t stream) {
  const float* x   = (const float*)d_in[0];
  const float* w1  = (const float*)d_in[1];
  const float* b1  = (const float*)d_in[2];
  const float* w2  = (const float*)d_in[3];
  const float* b2  = (const float*)d_in[4];
  const float* wc1 = (const float*)d_in[5];
  const float* bc1 = (const float*)d_in[6];
  const float* wc2 = (const float*)d_in[7];
  const float* bc2 = (const float*)d_in[8];
  const float* chr = (const float*)d_in[9];

  float* out = (float*)d_out;
  float* disp  = out;
  float* comb  = disp + (size_t)NTOK * EE * CAP;
  float* probs = comb + (size_t)NTOK * EE * CAP;
  float* aux   = probs + (size_t)NTOK * EE;

  float* ws = (float*)d_ws;
  float* psum   = ws + WS_PSUM;
  float* hcr    = ws + WS_HC;
  float* adj    = ws + WS_ADJ;
  float* p1     = ws + WS_P1;
  float* p2     = ws + WS_P2;
  int*   idxp   = (int*)(ws + WS_IDX);
  float* logits = ws + WS_LOGITS;           // fallback only
  float* avgp   = ws + WS_LOGITS;           // avg partials (mfma + fallback pre-gemm)

  char* wsb = (char*)d_ws;
  unsigned short* Xh = (unsigned short*)(wsb + WS_BF16_BYTE);
  unsigned short* Xm = Xh + (size_t)NTOK * HH;
  unsigned short* Xl = Xm + (size_t)NTOK * HH;
  unsigned short* Wh = Xl + (size_t)NTOK * HH;
  unsigned short* Wm = Wh + (size_t)HH * HH;
  unsigned short* Wl = Wm + (size_t)HH * HH;
  float* plg = (float*)(wsb + WS_H_BYTE);   // partial logits [32][4096][8]

  bool use_mfma = ws_size >= WS_NEED;

  if (use_mfma) {
    // D1: prep_x + prep_w + avg partials + ws-head zero, one dispatch
    k_prep<<<PREPX_BLKS + PREPW_BLKS + AVG_BLKS, 256, 0, stream>>>(
        x, w1, Xh, Xm, Xl, Wh, Wm, Wl, ws, avgp);
    // D2: hc (atomics into hc_raw zeroed in D1)
    k_hc<<<dim3(HH / 256, 8, BB), 256, 0, stream>>>(avgp, chr, wc1, hcr);
    // D3: 512 GEMM blocks (in-loop NT zeroing; plg epilogue) + 2 adj blocks
    k_gemm_mfma<<<dim3(NTOK / BM, HH / BN + 1), 256, 0, stream>>>(
        Xh, Xm, Xl, Wh, Wm, Wl, b1, w2, plg, (f32x4*)d_out,
        hcr, bc1, wc2, bc2, adj);
    // D4: slice-sum + softmax + top2 + psum (16 blocks)
    k_logits2<<<NTOK / 256, 256, 0, stream>>>(plg, b2, adj, probs, idxp, p1, p2, psum);
  } else {
    hipMemsetAsync(d_ws, 0, WS_ZERO_BYTES, stream);
    hipMemsetAsync(d_out, 0, (size_t)out_size * sizeof(float), stream);
    k_avgp<<<dim3(HH / 256, 16, BB), 256, 0, stream>>>(x, avgp);
    k_hc<<<dim3(HH / 256, 8, BB), 256, 0, stream>>>(avgp, chr, wc1, hcr);
    k_adj<<<BB, 256, 0, stream>>>(hcr, bc1, wc2, bc2, adj);
    k_init_logits<<<(NTOK * EE) / 256, 256, 0, stream>>>(adj, b2, logits);
    k_gemm_f32<<<dim3(NTOK / 64, HH / 64), 256, 0, stream>>>(x, w1, b1, w2, logits);
    k_softmax<<<NTOK / 256, 256, 0, stream>>>(logits, probs, idxp, p1, p2, psum);
  }
  // D5: serial-order capacity + scatter + aux
  k_route<<<1, 256, 0, stream>>>(idxp, p1, p2, psum, disp, comb, aux);
}